// Round 1
// 3385.108 us; speedup vs baseline: 1.3948x; 1.3948x over previous
//
#include <hip/hip_runtime.h>
#include <hip/hip_bf16.h>

constexpr int BATCH = 2, SEQ = 1024, EMB = 384, NH = 6, HSZ = 64, NLAYER = 3, VOC = 50257;
constexpr int BT = BATCH * SEQ;          // 2048
constexpr int BTC = BT * EMB;            // 786432
constexpr int WSZ = NLAYER * EMB * EMB;  // packed per-proj weight size = 442368

enum { F_BT = 1, F_BIAS = 2, F_RELU = 4, F_RES = 8, F_CAUSAL = 16 };

#define TS 64
#define KT 16

typedef __attribute__((ext_vector_type(8))) short short8;
typedef __attribute__((ext_vector_type(4))) float f32x4;

// async global->LDS, 16B per lane. LDS dest = wave-uniform base + lane*16
// (our per-lane pointers are contiguous per wave, so lane0's pointer == wave base).
#define GLD_LDS16(g, l) __builtin_amdgcn_global_load_lds( \
    (const __attribute__((address_space(1))) void*)(g),   \
    (__attribute__((address_space(3))) void*)(l), 16, 0, 0)

__device__ inline unsigned short f2bf_rne(float x) {
    unsigned u = __float_as_uint(x);
    unsigned r = (u + 0x7fffu + ((u >> 16) & 1u)) >> 16;
    return (unsigned short)r;
}

__global__ __launch_bounds__(256) void gemm_k(
    const float* __restrict__ A, int lda,
    const float* __restrict__ Bm, int ldb,
    const float* __restrict__ bias,
    const float* __restrict__ R,
    float* __restrict__ D, int ldd,
    int M, int N, int K, int flags, float scale,
    int zdiv,
    long long sA1, long long sA2, long long sB1, long long sB2,
    long long sD1, long long sD2)
{
    __shared__ float As[KT][TS + 4];
    __shared__ float Bs[KT][TS + 4];

    int z = blockIdx.z;
    int zb = z / zdiv, zh = z - zb * zdiv;
    A += zb * sA1 + zh * sA2;
    Bm += zb * sB1 + zh * sB2;
    long long doff = zb * sD1 + zh * sD2;
    D += doff;
    if (R) R += doff;

    int tx = threadIdx.x, ty = threadIdx.y;
    int tid = ty * 16 + tx;
    int m0 = blockIdx.y * TS;
    int n0 = blockIdx.x * TS;

    float acc[4][4] = {};

    for (int k0 = 0; k0 < K; k0 += KT) {
        // A tile: TS x KT  -> As[kk][mm]
        #pragma unroll
        for (int i = 0; i < 4; i++) {
            int lin = tid + i * 256;        // 0..1023
            int mm = lin >> 4;
            int kk = lin & 15;
            int gm = m0 + mm, gk = k0 + kk;
            As[kk][mm] = (gm < M && gk < K) ? A[(size_t)gm * lda + gk] : 0.f;
        }
        // B tile: KT x TS -> Bs[kk][nn]
        if (flags & F_BT) {
            #pragma unroll
            for (int i = 0; i < 4; i++) {
                int lin = tid + i * 256;
                int nn = lin >> 4;
                int kk = lin & 15;
                int gn = n0 + nn, gk = k0 + kk;
                Bs[kk][nn] = (gn < N && gk < K) ? Bm[(size_t)gn * ldb + gk] : 0.f;
            }
        } else {
            #pragma unroll
            for (int i = 0; i < 4; i++) {
                int lin = tid + i * 256;
                int kk = lin >> 6;
                int nn = lin & 63;
                int gn = n0 + nn, gk = k0 + kk;
                Bs[kk][nn] = (gn < N && gk < K) ? Bm[(size_t)gk * ldb + gn] : 0.f;
            }
        }
        __syncthreads();

        #pragma unroll
        for (int kk = 0; kk < KT; kk++) {
            float a_[4], b_[4];
            #pragma unroll
            for (int i = 0; i < 4; i++) a_[i] = As[kk][ty * 4 + i];
            #pragma unroll
            for (int j = 0; j < 4; j++) b_[j] = Bs[kk][tx * 4 + j];
            #pragma unroll
            for (int i = 0; i < 4; i++)
                #pragma unroll
                for (int j = 0; j < 4; j++)
                    acc[i][j] += a_[i] * b_[j];
        }
        __syncthreads();
    }

    #pragma unroll
    for (int i = 0; i < 4; i++) {
        int gm = m0 + ty * 4 + i;
        if (gm >= M) continue;
        #pragma unroll
        for (int j = 0; j < 4; j++) {
            int gn = n0 + tx * 4 + j;
            if (gn >= N) continue;
            float v = acc[i][j];
            if (flags & F_CAUSAL) { v *= scale; if (gn > gm) v = -1e30f; }
            if (flags & F_BIAS) v += bias[gn];
            if (flags & F_RELU) v = fmaxf(v, 0.f);
            if (flags & F_RES)  v += R[(size_t)gm * ldd + gn];
            D[(size_t)gm * ldd + gn] = v;
        }
    }
}

__global__ void embed_k(const int* __restrict__ x, const float* __restrict__ tok,
                        const float* __restrict__ pos, float* __restrict__ h)
{
    int idx = blockIdx.x * blockDim.x + threadIdx.x;
    if (idx >= BT * EMB) return;
    int c = idx % EMB;
    int bt = idx / EMB;
    int t = bt % SEQ;
    h[idx] = tok[(size_t)x[bt] * EMB + c] + pos[(size_t)t * EMB + c];
}

// pack Wq/Wk/Wv from (NL,H,C,HS) to (NL, C, H*HS) row-major
__global__ void repack_k(const float* __restrict__ Wq, const float* __restrict__ Wk,
                         const float* __restrict__ Wv,
                         float* __restrict__ Pq, float* __restrict__ Pk, float* __restrict__ Pv)
{
    int idx = blockIdx.x * blockDim.x + threadIdx.x;
    if (idx >= NLAYER * NH * EMB * HSZ) return;
    int s = idx % HSZ;
    int c = (idx / HSZ) % EMB;
    int hh = (idx / (HSZ * EMB)) % NH;
    int l = idx / (HSZ * EMB * NH);
    int dst = (l * EMB + c) * EMB + hh * HSZ + s;
    Pq[dst] = Wq[idx];
    Pk[dst] = Wk[idx];
    Pv[dst] = Wv[idx];
}

__global__ __launch_bounds__(128) void layernorm_k(const float* __restrict__ X,
                                                   const float* __restrict__ g,
                                                   const float* __restrict__ b,
                                                   float* __restrict__ Y)
{
    int row = blockIdx.x;
    int tid = threadIdx.x;
    const float* xr = X + (size_t)row * EMB;
    float v0 = xr[tid], v1 = xr[tid + 128], v2 = xr[tid + 256];
    float s = v0 + v1 + v2;
    float s2 = v0 * v0 + v1 * v1 + v2 * v2;
    __shared__ float ss[128], sq[128];
    ss[tid] = s; sq[tid] = s2;
    __syncthreads();
    for (int off = 64; off > 0; off >>= 1) {
        if (tid < off) { ss[tid] += ss[tid + off]; sq[tid] += sq[tid + off]; }
        __syncthreads();
    }
    float mu = ss[0] * (1.0f / EMB);
    float var = sq[0] * (1.0f / EMB) - mu * mu;
    float r = rsqrtf(var + 1e-5f);
    float* yr = Y + (size_t)row * EMB;
    yr[tid]       = (v0 - mu) * r * g[tid]       + b[tid];
    yr[tid + 128] = (v1 - mu) * r * g[tid + 128] + b[tid + 128];
    yr[tid + 256] = (v2 - mu) * r * g[tid + 256] + b[tid + 256];
}

// softmax over the QUERY axis: for each (b,h,key) column, normalize over t (stride SEQ)
__global__ void softmax_q_k(float* __restrict__ w)
{
    int col = blockIdx.x * blockDim.x + threadIdx.x;
    if (col >= BATCH * NH * SEQ) return;
    int bh = col / SEQ, k = col % SEQ;
    float* base = w + (size_t)bh * SEQ * SEQ + k;
    float mx = -1e30f;
    for (int t = 0; t < SEQ; t++) mx = fmaxf(mx, base[(size_t)t * SEQ]);
    float sum = 0.f;
    for (int t = 0; t < SEQ; t++) sum += __expf(base[(size_t)t * SEQ] - mx);
    float inv = 1.0f / sum;
    for (int t = 0; t < SEQ; t++)
        base[(size_t)t * SEQ] = __expf(base[(size_t)t * SEQ] - mx) * inv;
}

// ---------------- LM head: bf16x2-split MFMA GEMM ----------------

// split fp32 -> bf16 hi + bf16 lo (residual)
__global__ void split_bf16_k(const float* __restrict__ X,
                             unsigned short* __restrict__ Hi,
                             unsigned short* __restrict__ Lo, int n)
{
    int i = blockIdx.x * blockDim.x + threadIdx.x;
    if (i >= n) return;
    float x = X[i];
    unsigned short h = f2bf_rne(x);
    float hf = __uint_as_float((unsigned)h << 16);
    Hi[i] = h;
    Lo[i] = f2bf_rne(x - hf);
}

// Wlm [K=EMB][N=VOC] row-major fp32  ->  Bt [N][K] bf16 (hi only)
__global__ __launch_bounds__(256) void transpose_bf16_k(const float* __restrict__ W,
                                                        unsigned short* __restrict__ T)
{
    __shared__ float tile[32][33];
    int n0 = blockIdx.x * 32, k0 = blockIdx.y * 32;
    int tx = threadIdx.x, ty = threadIdx.y;   // 32 x 8
    #pragma unroll
    for (int r = 0; r < 32; r += 8) {
        int k = k0 + ty + r, n = n0 + tx;     // k < EMB always (384 % 32 == 0)
        tile[ty + r][tx] = (n < VOC) ? W[(size_t)k * VOC + n] : 0.f;
    }
    __syncthreads();
    #pragma unroll
    for (int r = 0; r < 32; r += 8) {
        int n = n0 + ty + r, k = k0 + tx;
        if (n < VOC) T[(size_t)n * EMB + k] = f2bf_rne(tile[tx][ty + r]);
    }
}

// D[M=BT][N=VOC] = (Ahi+Alo) @ Bt^T + bias
// Tile 128x128, BK=32, 4 waves (2x2), each wave 64x64 via 4x4 of 16x16x32 MFMA.
// LDS layout per tile: [k-slot(4)][row(128)][8 bf16] -- linear for global_load_lds,
// conflict-free on ds_read_b128 fragment reads (16 lanes * 16B = all 32 banks).
__global__ __launch_bounds__(256) void lmhead_k(
    const unsigned short* __restrict__ Ahi,
    const unsigned short* __restrict__ Alo,
    const unsigned short* __restrict__ Bt,
    const float* __restrict__ bias,
    float* __restrict__ D)
{
    __shared__ unsigned short sA[4096];  // 8 KB
    __shared__ unsigned short sL[4096];
    __shared__ unsigned short sB[4096];

    int tid  = threadIdx.x;
    int lane = tid & 63, w = tid >> 6;
    int wr = w >> 1, wc = w & 1;
    int m0 = blockIdx.y * 128, n0 = blockIdx.x * 128;
    int lr = lane & 15, lk = lane >> 4;

    f32x4 acc[4][4] = {};

    for (int k0 = 0; k0 < EMB; k0 += 32) {
        #pragma unroll
        for (int q = 0; q < 2; q++) {
            int idx = q * 256 + tid;          // 0..511
            int ko = idx >> 7, row = idx & 127;
            size_t koff = (size_t)(k0 + ko * 8);
            GLD_LDS16(Ahi + (size_t)(m0 + row) * EMB + koff, &sA[idx * 8]);
            GLD_LDS16(Alo + (size_t)(m0 + row) * EMB + koff, &sL[idx * 8]);
            int gn = n0 + row; if (gn > VOC - 1) gn = VOC - 1;   // clamp edge tile
            GLD_LDS16(Bt + (size_t)gn * EMB + koff, &sB[idx * 8]);
        }
        __syncthreads();   // compiler drains vmcnt before s_barrier

        const short8* pA = (const short8*)sA;
        const short8* pL = (const short8*)sL;
        const short8* pB = (const short8*)sB;
        short8 a_[4], l_[4], b_[4];
        #pragma unroll
        for (int i = 0; i < 4; i++) a_[i] = pA[lk * 128 + wr * 64 + i * 16 + lr];
        #pragma unroll
        for (int i = 0; i < 4; i++) l_[i] = pL[lk * 128 + wr * 64 + i * 16 + lr];
        #pragma unroll
        for (int j = 0; j < 4; j++) b_[j] = pB[lk * 128 + wc * 64 + j * 16 + lr];

        #pragma unroll
        for (int i = 0; i < 4; i++)
            #pragma unroll
            for (int j = 0; j < 4; j++) {
                acc[i][j] = __builtin_amdgcn_mfma_f32_16x16x32_bf16(a_[i], b_[j], acc[i][j], 0, 0, 0);
                acc[i][j] = __builtin_amdgcn_mfma_f32_16x16x32_bf16(l_[i], b_[j], acc[i][j], 0, 0, 0);
            }
        __syncthreads();
    }

    // C/D layout (verified m89/m91): col = lane&15, row = (lane>>4)*4 + reg
    int mrow = m0 + wr * 64 + lk * 4;
    int ncb  = n0 + wc * 64 + lr;
    #pragma unroll
    for (int j = 0; j < 4; j++) {
        int gn = ncb + j * 16;
        if (gn >= VOC) continue;
        float bb = bias[gn];
        #pragma unroll
        for (int i = 0; i < 4; i++) {
            size_t rbase = (size_t)(mrow + i * 16) * VOC + gn;
            #pragma unroll
            for (int r = 0; r < 4; r++)
                D[rbase + (size_t)r * VOC] = acc[i][j][r] + bb;
        }
    }
}

extern "C" void kernel_launch(void* const* d_in, const int* in_sizes, int n_in,
                              void* d_out, int out_size, void* d_ws, size_t ws_size,
                              hipStream_t stream)
{
    const int*   x    = (const int*)d_in[0];
    const float* tok  = (const float*)d_in[1];
    const float* pos  = (const float*)d_in[2];
    const float* Wq   = (const float*)d_in[3];
    const float* bq   = (const float*)d_in[4];
    const float* Wk   = (const float*)d_in[5];
    const float* bk   = (const float*)d_in[6];
    const float* Wv   = (const float*)d_in[7];
    const float* bv   = (const float*)d_in[8];
    const float* Wo   = (const float*)d_in[9];
    const float* bo   = (const float*)d_in[10];
    const float* ln1g = (const float*)d_in[11];
    const float* ln1b = (const float*)d_in[12];
    const float* W1   = (const float*)d_in[13];
    const float* b1   = (const float*)d_in[14];
    const float* W2   = (const float*)d_in[15];
    const float* b2   = (const float*)d_in[16];
    const float* ln2g = (const float*)d_in[17];
    const float* ln2b = (const float*)d_in[18];
    const float* Wlm  = (const float*)d_in[19];
    const float* blm  = (const float*)d_in[20];
    float* out = (float*)d_out;

    float* ws = (float*)d_ws;
    float* h    = ws;
    float* a    = ws + (size_t)1 * BTC;
    float* q    = ws + (size_t)2 * BTC;
    float* kbuf = ws + (size_t)3 * BTC;
    float* vbuf = ws + (size_t)4 * BTC;
    float* attc = ws + (size_t)5 * BTC;
    float* m1   = ws + (size_t)6 * BTC;
    float* Pq   = ws + (size_t)7 * BTC;
    float* Pk   = Pq + WSZ;
    float* Pv   = Pk + WSZ;
    float* sc   = Pv + WSZ;   // scores: BATCH*NH*SEQ*SEQ floats (48 MB)

    dim3 blk2(16, 16);
    auto gemm = [&](const float* A, int lda, const float* Bm, int ldb,
                    const float* bias, const float* R, float* D, int ldd,
                    int M, int N, int K, int flags, float scale,
                    int gz, int zdiv,
                    long long sA1, long long sA2, long long sB1, long long sB2,
                    long long sD1, long long sD2) {
        dim3 grid((N + TS - 1) / TS, (M + TS - 1) / TS, gz);
        gemm_k<<<grid, blk2, 0, stream>>>(A, lda, Bm, ldb, bias, R, D, ldd,
                                          M, N, K, flags, scale, zdiv,
                                          sA1, sA2, sB1, sB2, sD1, sD2);
    };

    embed_k<<<(BT * EMB + 255) / 256, 256, 0, stream>>>(x, tok, pos, h);
    repack_k<<<(NLAYER * NH * EMB * HSZ + 255) / 256, 256, 0, stream>>>(Wq, Wk, Wv, Pq, Pk, Pv);

    const float scale = 0.125f; // 1/sqrt(64)

    for (int l = 0; l < NLAYER; l++) {
        layernorm_k<<<BT, 128, 0, stream>>>(h, ln1g + l * EMB, ln1b + l * EMB, a);

        gemm(a, EMB, Pq + (size_t)l * EMB * EMB, EMB, bq + l * EMB, nullptr, q, EMB,
             BT, EMB, EMB, F_BIAS, 0.f, 1, 1, 0, 0, 0, 0, 0, 0);
        gemm(a, EMB, Pk + (size_t)l * EMB * EMB, EMB, bk + l * EMB, nullptr, kbuf, EMB,
             BT, EMB, EMB, F_BIAS, 0.f, 1, 1, 0, 0, 0, 0, 0, 0);
        gemm(a, EMB, Pv + (size_t)l * EMB * EMB, EMB, bv + l * EMB, nullptr, vbuf, EMB,
             BT, EMB, EMB, F_BIAS, 0.f, 1, 1, 0, 0, 0, 0, 0, 0);

        // scores[b,h,t,k] = scale * q.kT, causal-masked   (batched over z = b*NH+h)
        gemm(q, EMB, kbuf, EMB, nullptr, nullptr, sc, SEQ,
             SEQ, SEQ, HSZ, F_BT | F_CAUSAL, scale, BATCH * NH, NH,
             (long long)SEQ * EMB, HSZ,            // A strides (per-b, per-h)
             (long long)SEQ * EMB, HSZ,            // B strides
             (long long)NH * SEQ * SEQ, (long long)SEQ * SEQ);  // D strides

        softmax_q_k<<<(BATCH * NH * SEQ + 255) / 256, 256, 0, stream>>>(sc);

        // att = w @ v  -> attc (B*T, C) with col = h*HS + s
        gemm(sc, SEQ, vbuf, EMB, nullptr, nullptr, attc, EMB,
             SEQ, HSZ, SEQ, 0, 0.f, BATCH * NH, NH,
             (long long)NH * SEQ * SEQ, (long long)SEQ * SEQ,
             (long long)SEQ * EMB, HSZ,
             (long long)SEQ * EMB, HSZ);

        // h = h + attc @ Wo + bo
        gemm(attc, EMB, Wo + (size_t)l * EMB * EMB, EMB, bo + l * EMB, h, h, EMB,
             BT, EMB, EMB, F_BIAS | F_RES, 0.f, 1, 1, 0, 0, 0, 0, 0, 0);

        layernorm_k<<<BT, 128, 0, stream>>>(h, ln2g + l * EMB, ln2b + l * EMB, a);

        // m1 = relu(a @ W1 + b1)
        gemm(a, EMB, W1 + (size_t)l * EMB * EMB, EMB, b1 + l * EMB, nullptr, m1, EMB,
             BT, EMB, EMB, F_BIAS | F_RELU, 0.f, 1, 1, 0, 0, 0, 0, 0, 0);

        // h = h + m1 @ W2 + b2
        gemm(m1, EMB, W2 + (size_t)l * EMB * EMB, EMB, b2 + l * EMB, h, h, EMB,
             BT, EMB, EMB, F_BIAS | F_RES, 0.f, 1, 1, 0, 0, 0, 0, 0, 0);
    }

    // ---- LM head via MFMA (bf16x2 split) ----
    // All workspace slots except h are dead now; overlay bf16 buffers there.
    unsigned short* AhiW = (unsigned short*)a;     // 1.5 MB in a 3 MB slot
    unsigned short* AloW = (unsigned short*)q;     // 1.5 MB in a 3 MB slot
    unsigned short* BtW  = (unsigned short*)vbuf;  // 38.6 MB in the dead 62 MB region

    split_bf16_k<<<(BTC + 255) / 256, 256, 0, stream>>>(h, AhiW, AloW, BTC);
    transpose_bf16_k<<<dim3((VOC + 31) / 32, EMB / 32), dim3(32, 8), 0, stream>>>(Wlm, BtW);

    dim3 lmgrid((VOC + 127) / 128, BT / 128);   // 393 x 16
    lmhead_k<<<lmgrid, 256, 0, stream>>>(AhiW, AloW, BtW, blm, out);
}